// Round 18
// baseline (41.949 us; speedup 1.0000x reference)
//
#include <hip/hip_runtime.h>
#include <math.h>

#define NN 1024
#define DD 64
#define HH 256
#define TEMP_INV 10.0f
#define KCH 64
#define NCH 4
#define NBLK2 1024u

// ws layout (floats):
//   x2T [HH][NN] : xp + b1, k-major     1 MB
//   y2  [NN][HH] : yp, row-major        1 MB
//   E   [NN]     : per-row sum(exp(score)) (fixed max = 0)
//   gacc[2], tick (u32)
//
// R16 fan-in structure; k2 re-tiled 2x2/thread: 32x32 tile, grid 32x32 =
// 4096 waves = 4 waves/SIMD (true occupancy doubling vs R12/R17's 2048).

__global__ __launch_bounds__(256)
void k1_proj(const float* __restrict__ x, const float* __restrict__ y,
             const float* __restrict__ W1, const float* __restrict__ b1,
             float* __restrict__ x2T, float* __restrict__ y2,
             float* __restrict__ E, float* __restrict__ gacc,
             unsigned int* __restrict__ tick)
{
    const int tid = threadIdx.x;        // h index 0..255
    if (blockIdx.x == 0) {              // re-arm accumulators every call
        *(float4*)&E[tid * 4] = make_float4(0.f, 0.f, 0.f, 0.f);
        if (tid == 0) { gacc[0] = 0.f; gacc[1] = 0.f; tick[0] = 0u; }
    }
    const int i0 = blockIdx.x * 2;      // 2 rows per block -> 512 blocks
    float ax0 = 0.f, ax1 = 0.f, ay0 = 0.f, ay1 = 0.f;
    #pragma unroll 8
    for (int kk = 0; kk < DD; ++kk) {
        const float wx = W1[kk * HH + tid];
        const float wy = W1[(DD + kk) * HH + tid];
        ax0 = fmaf(x[i0 * DD + kk],       wx, ax0);
        ax1 = fmaf(x[(i0 + 1) * DD + kk], wx, ax1);
        ay0 = fmaf(y[i0 * DD + kk],       wy, ay0);
        ay1 = fmaf(y[(i0 + 1) * DD + kk], wy, ay1);
    }
    const float b1t = b1[tid];
    *(float2*)&x2T[tid * NN + i0] = make_float2(ax0 + b1t, ax1 + b1t);
    y2[i0 * HH + tid]       = ay0;      // coalesced over tid
    y2[(i0 + 1) * HH + tid] = ay1;
}

__global__ __launch_bounds__(256, 4)
void k2_scores(const float* __restrict__ x2T, const float* __restrict__ y2,
               const float* __restrict__ w2, const float* __restrict__ b2,
               float* __restrict__ E, float* __restrict__ gacc,
               unsigned int* __restrict__ tick, float* __restrict__ out)
{
    __shared__ float xs[2][KCH][32];   // 16 KB, double-buffered
    __shared__ float redf[256];
    __shared__ unsigned int s_old;
    const int t  = threadIdx.x;        // 0..255
    const int bj = blockIdx.x;         // 0..31 -> 32 cols
    const int bi = blockIdx.y;         // 0..31 -> 32 rows
    const int j0 = bj * 32;
    const int rr = t >> 4;             // 0..15 -> rows rbase, rbase+1
    const int cc = t & 15;             // 0..15 -> cols col0, col0+1
    const int rbase = bi * 32 + rr * 2;
    const float* yb = y2 + rbase * HH;

    const int wv  = t >> 6;            // wave id 0..3 (wave-uniform)
    const int ln  = t & 63;
    const int sro = ln >> 3;           // 0..7
    const int sco = (ln & 7) * 4;      // 0,4,..,28

    float a00 = 0.f, a01 = 0.f, a10 = 0.f, a11 = 0.f;

    // stage chunk c into buffer b: wave covers 8 rows x 32 cols per call,
    // 2 calls -> 16 rows per wave, 4 waves -> 64 rows. Dest linear.
    #define STAGE(c, b)                                                        \
    {                                                                          \
        _Pragma("unroll")                                                      \
        for (int h = 0; h < 2; ++h) {                                          \
            const int row = wv * 16 + h * 8;                                   \
            const float* gsrc =                                               \
                &x2T[((c) * KCH + row + sro) * NN + j0 + sco];                 \
            __builtin_amdgcn_global_load_lds(                                  \
                (const __attribute__((address_space(1))) unsigned int*)gsrc,   \
                (__attribute__((address_space(3))) unsigned int*)&xs[b][row][0],\
                16, 0, 0);                                                     \
        }                                                                      \
    }

    STAGE(0, 0);
    for (int c = 0; c < NCH; ++c) {
        __syncthreads();
        if (c + 1 < NCH) STAGE(c + 1, (c + 1) & 1);
        const int cur = c & 1;
        #pragma unroll
        for (int g = 0; g < 16; ++g) {
            const int gg = c * 16 + g;
            const float4 y0 = *(const float4*)&yb[gg * 4];
            const float4 y1 = *(const float4*)&yb[HH + gg * 4];
            #pragma unroll
            for (int e = 0; e < 4; ++e) {
                const float wk = w2[gg * 4 + e];      // uniform -> s_load
                const float2 xv = *(const float2*)&xs[cur][g * 4 + e][cc * 2];
                const float yv0 = (e == 0) ? y0.x : (e == 1) ? y0.y
                                : (e == 2) ? y0.z : y0.w;
                const float yv1 = (e == 0) ? y1.x : (e == 1) ? y1.y
                                : (e == 2) ? y1.z : y1.w;
                a00 = fmaf(fmaxf(yv0 + xv.x, 0.f), wk, a00);
                a01 = fmaf(fmaxf(yv0 + xv.y, 0.f), wk, a01);
                a10 = fmaf(fmaxf(yv1 + xv.x, 0.f), wk, a10);
                a11 = fmaf(fmaxf(yv1 + xv.y, 0.f), wk, a11);
            }
        }
    }
    #undef STAGE

    // ---- epilogue: fixed-max (M0=0) exp-sums + atomic fan-in ----
    const float bb = b2[0];
    const float s00 = (a00 + bb) * TEMP_INV;
    const float s01 = (a01 + bb) * TEMP_INV;
    const float s10 = (a10 + bb) * TEMP_INV;
    const float s11 = (a11 + bb) * TEMP_INV;

    const int col0 = j0 + cc * 2;
    float dv = 0.f; bool isd = false;
    if (rbase == col0)         { dv += s00; isd = true; }
    if (rbase == col0 + 1)     { dv += s01; isd = true; }
    if (rbase + 1 == col0)     { dv += s10; isd = true; }
    if (rbase + 1 == col0 + 1) { dv += s11; isd = true; }
    if (isd) atomicAdd(&gacc[1], dv);

    float e0 = __expf(s00) + __expf(s01);
    float e1 = __expf(s10) + __expf(s11);
    #pragma unroll
    for (int mk = 8; mk >= 1; mk >>= 1) {   // reduce over cc (16 lanes)
        e0 += __shfl_xor(e0, mk);
        e1 += __shfl_xor(e1, mk);
    }
    if (cc == 0) {
        atomicAdd(&E[rbase],     e0);
        atomicAdd(&E[rbase + 1], e1);
    }

    // ---- ticket fan-in: last block finalizes (no fences, no spin) ----
    asm volatile("s_waitcnt vmcnt(0)" ::: "memory");
    __syncthreads();
    if (t == 0) s_old = atomicAdd(tick, 1u);
    __syncthreads();
    if (s_old == NBLK2 - 1u) {
        float ls = 0.f;
        #pragma unroll
        for (int r = 0; r < 4; ++r) {
            const float ev = __hip_atomic_load(&E[t + r * 256],
                                               __ATOMIC_RELAXED,
                                               __HIP_MEMORY_SCOPE_AGENT);
            ls += logf(ev);
        }
        redf[t] = ls;
        __syncthreads();
        for (int s2 = 128; s2 > 0; s2 >>= 1) {
            if (t < s2) redf[t] += redf[t + s2];
            __syncthreads();
        }
        if (t == 0) {
            const float pos_sum = __hip_atomic_load(&gacc[1], __ATOMIC_RELAXED,
                                                    __HIP_MEMORY_SCOPE_AGENT);
            out[0] = redf[0] / (float)NN - logf((float)NN)
                   - pos_sum / (float)NN;
        }
    }
}

extern "C" void kernel_launch(void* const* d_in, const int* in_sizes, int n_in,
                              void* d_out, int out_size, void* d_ws, size_t ws_size,
                              hipStream_t stream)
{
    const float* x  = (const float*)d_in[0];
    const float* y  = (const float*)d_in[1];
    const float* W1 = (const float*)d_in[2];
    const float* b1 = (const float*)d_in[3];
    const float* w2 = (const float*)d_in[4];
    const float* b2 = (const float*)d_in[5];
    float* out = (float*)d_out;

    float* ws   = (float*)d_ws;
    float* x2T  = ws;                 // 256*1024
    float* y2   = x2T + HH * NN;      // 1024*256
    float* E    = y2 + NN * HH;       // 1024
    float* gacc = E + NN;             // 2
    unsigned int* tick = (unsigned int*)(gacc + 2);

    hipLaunchKernelGGL(k1_proj, dim3(NN / 2), dim3(256), 0, stream,
                       x, y, W1, b1, x2T, y2, E, gacc, tick);
    hipLaunchKernelGGL(k2_scores, dim3(32, 32), dim3(256), 0, stream,
                       x2T, y2, w2, b2, E, gacc, tick, out);
}